// Round 11
// baseline (169.286 us; speedup 1.0000x reference)
//
#include <hip/hip_runtime.h>

#define GAS __attribute__((address_space(1)))
#define LAS __attribute__((address_space(3)))

typedef __attribute__((ext_vector_type(8))) short short8;
typedef __attribute__((ext_vector_type(4))) float f32x4;
typedef unsigned short u16;

constexpr int cB = 16, cC = 256, cIC = 128, cN = 1024;

__device__ __forceinline__ u16 f2bf(float v) {
    unsigned u = __builtin_bit_cast(unsigned, v);
    return (u16)((u + 0x7fffu + ((u >> 16) & 1u)) >> 16);
}
__device__ __forceinline__ float bf2f(u16 v) {
    unsigned u = ((unsigned)v) << 16;
    return __builtin_bit_cast(float, u);
}
__device__ __forceinline__ float rsz(float d) {
    return (d != 0.0f) ? rsqrtf(d) : 0.0f;
}

template<int N> __device__ __forceinline__ void wait_vmcnt() {
    if constexpr (N == 0) asm volatile("s_waitcnt vmcnt(0)" ::: "memory");
    else if constexpr (N == 1) asm volatile("s_waitcnt vmcnt(1)" ::: "memory");
    else if constexpr (N == 2) asm volatile("s_waitcnt vmcnt(2)" ::: "memory");
    else if constexpr (N == 3) asm volatile("s_waitcnt vmcnt(3)" ::: "memory");
    else if constexpr (N == 4) asm volatile("s_waitcnt vmcnt(4)" ::: "memory");
    else if constexpr (N == 5) asm volatile("s_waitcnt vmcnt(5)" ::: "memory");
    else if constexpr (N == 6) asm volatile("s_waitcnt vmcnt(6)" ::: "memory");
    else if constexpr (N == 8) asm volatile("s_waitcnt vmcnt(8)" ::: "memory");
}

// ---------------------------------------------------------------------------
// Double-buffered prefetch GEMM core with LDS XOR-swizzle (2-way max).
// C[m,n] = sum_k A[m,k]*B[n,k]  (both K-major).
// Dual-A: for kk >= ksplit reads Ab2 + (kk - ksplit).
// BREMAP: B column for k-chunk kk is ((kk>>7)<<8)+(kk&127).
// ---------------------------------------------------------------------------
template<int BM, int BN, int WR, int WC, bool BREMAP = false>
__device__ __forceinline__ void gemm_core(
    const u16* __restrict__ Ab, const u16* __restrict__ Ab2, int ksplit, int lda,
    const u16* __restrict__ Bb, int ldb, int K,
    u16* lsA, u16* lsB,
    f32x4 (&acc)[BM/(WR*16)][BN/(WC*16)])
{
    constexpr int THREADS = WR * WC * 64;
    constexpr int MR = BM / (WR * 16), NR = BN / (WC * 16);
    constexpr int ACH = (BM * 64) / (THREADS * 16);
    constexpr int BCH = (BN * 64) / (THREADS * 16);
    constexpr int RPC = THREADS / 4;
    constexpr int ISSUES = ACH + BCH;

    const int tid  = threadIdx.x;
    const int lane = tid & 63;
    const int wave = tid >> 6;
    const int wr = wave / WC, wc = wave % WC;
    const int r0 = tid >> 2, slot = tid & 3;

    auto stage = [&](int buf, int kk) {
        const u16* Ak = (Ab2 != nullptr && kk >= ksplit) ? (Ab2 + (kk - ksplit)) : (Ab + kk);
        const u16* Bk = Bb + (BREMAP ? (((kk >> 7) << 8) + (kk & 127)) : kk);
        #pragma unroll
        for (int c = 0; c < ACH; c++) {
            int row = c * RPC + r0;
            int sk = (slot ^ ((row >> 1) & 3)) << 3;
            __builtin_amdgcn_global_load_lds((GAS void*)(Ak + (size_t)row * lda + sk),
                (LAS void*)(lsA + buf * (BM * 32) + c * (THREADS * 8) + (wave << 9)), 16, 0, 0);
        }
        #pragma unroll
        for (int c = 0; c < BCH; c++) {
            int row = c * RPC + r0;
            int sk = (slot ^ ((row >> 1) & 3)) << 3;
            __builtin_amdgcn_global_load_lds((GAS void*)(Bk + (size_t)row * ldb + sk),
                (LAS void*)(lsB + buf * (BN * 32) + c * (THREADS * 8) + (wave << 9)), 16, 0, 0);
        }
    };

    stage(0, 0);
    const int nt = K >> 5;
    for (int t = 0; t < nt; t++) {
        const int cur = t & 1;
        if (t + 1 < nt) { stage(cur ^ 1, (t + 1) << 5); wait_vmcnt<ISSUES>(); }
        else            wait_vmcnt<0>();
        __builtin_amdgcn_s_barrier();
        asm volatile("" ::: "memory");

        const u16* la = lsA + cur * (BM * 32);
        const u16* lb = lsB + cur * (BN * 32);
        short8 af[MR], bf[NR];
        #pragma unroll
        for (int m = 0; m < MR; m++) {
            int row = wr * (BM / WR) + (m << 4) + (lane & 15);
            af[m] = *(const short8*)&la[(row << 5) + (((lane >> 4) ^ ((row >> 1) & 3)) << 3)];
        }
        #pragma unroll
        for (int n = 0; n < NR; n++) {
            int row = wc * (BN / WC) + (n << 4) + (lane & 15);
            bf[n] = *(const short8*)&lb[(row << 5) + (((lane >> 4) ^ ((row >> 1) & 3)) << 3)];
        }
        #pragma unroll
        for (int m = 0; m < MR; m++)
            #pragma unroll
            for (int n = 0; n < NR; n++)
                acc[m][n] = __builtin_amdgcn_mfma_f32_16x16x32_bf16(af[m], bf[n], acc[m][n], 0, 0, 0);

        asm volatile("s_waitcnt lgkmcnt(0)" ::: "memory");
        __builtin_amdgcn_sched_barrier(0);
        __builtin_amdgcn_s_barrier();
    }
}

// ---------------------------------------------------------------------------
// tp_gemm: TP[z][n][c] = relu(XT @ WTP^T) with fused column sums (over n)
// -> CS[z][c]. 384 blocks of 512 threads, tile 128x256.
// ---------------------------------------------------------------------------
__global__ __launch_bounds__(512) void tp_gemm(
    const u16* __restrict__ XT, const u16* __restrict__ WTP,
    u16* __restrict__ TP, float* __restrict__ CS)
{
    __shared__ alignas(16) u16 lsA[2 * 128 * 32];
    __shared__ alignas(16) u16 lsB[2 * 256 * 32];

    const int nx = blockIdx.x, z = blockIdx.z;
    const u16* Ab = XT + (size_t)z * 262144 + (size_t)(nx * 128) * 256;

    f32x4 acc[4][4] = {};
    gemm_core<128, 256, 2, 4>(Ab, nullptr, 256, 256, WTP, 256, 256, lsA, lsB, acc);

    const int lane = threadIdx.x & 63;
    const int wave = threadIdx.x >> 6;
    const int wr = wave >> 2, wc = wave & 3;
    const int rowb = nx * 128 + wr * 64 + ((lane >> 4) << 2);
    const int colb = wc * 64 + (lane & 15);
    u16* Cb = TP + (size_t)z * 262144;

    float cp[4] = {};
    #pragma unroll
    for (int m = 0; m < 4; m++)
        #pragma unroll
        for (int n = 0; n < 4; n++)
            #pragma unroll
            for (int r = 0; r < 4; r++) {
                float v = fmaxf(acc[m][n][r], 0.0f);
                Cb[(size_t)(rowb + m * 16 + r) * 256 + colb + n * 16] = f2bf(v);
                cp[n] += v;
            }
    #pragma unroll
    for (int n = 0; n < 4; n++) {
        float v = cp[n];
        v += __shfl_xor(v, 16, 64);
        v += __shfl_xor(v, 32, 64);
        if (lane < 16)
            atomicAdd(&CS[z * 256 + colb + n * 16], v);
    }
}

// ---------------------------------------------------------------------------
// tpt2: per block, 64 n-rows x all 256 c of TP. Computes d[n] fully in-block
// (d[n] = sum_c TP[n][c] * 0.5*CS[c^128]), then writes BOTH dv-scaled layouts:
//   TPS [z][n][c] (n-major) and TPSt [z][c][n] (c-major).
// grid (16,1,48), 256 threads. DINV never materialized.
// ---------------------------------------------------------------------------
__global__ __launch_bounds__(256) void tpt2(
    const u16* __restrict__ TP, const float* __restrict__ CS,
    u16* __restrict__ TPS, u16* __restrict__ TPSt)
{
    __shared__ u16 ls[64][264];     // row stride 264 (16B-aligned rows)
    __shared__ float ws[256];
    __shared__ float pd[64][4];
    __shared__ float dvs[64];

    const int z = blockIdx.z;
    const int n0 = blockIdx.x << 6;
    const int tid = threadIdx.x;

    ws[tid] = 0.5f * CS[z * 256 + (tid ^ 128)];

    const u16* src = TP + (size_t)z * 262144;
    #pragma unroll
    for (int k = 0; k < 8; k++) {
        int chunk = k * 256 + tid;
        int row = chunk >> 5, c8 = (chunk & 31) << 3;
        *(short8*)&ls[row][c8] = *(const short8*)&src[(size_t)(n0 + row) * 256 + c8];
    }
    __syncthreads();

    {
        const int row = tid >> 2, q = tid & 3;
        float a = 0;
        #pragma unroll 16
        for (int i = 0; i < 64; i++) {
            int c = q * 64 + i;
            a += bf2f(ls[row][c]) * ws[c];
        }
        pd[row][q] = a;
    }
    __syncthreads();
    if (tid < 64) {
        float d = pd[tid][0] + pd[tid][1] + pd[tid][2] + pd[tid][3];
        dvs[tid] = rsz(d);
    }
    __syncthreads();

    // TPS: n-major scaled (coalesced rows)
    u16* So = TPS + (size_t)z * 262144;
    #pragma unroll
    for (int k = 0; k < 8; k++) {
        int chunk = k * 256 + tid;
        int row = chunk >> 5, c8 = (chunk & 31) << 3;
        short8 v = *(const short8*)&ls[row][c8];
        float s = dvs[row];
        short8 o;
        #pragma unroll
        for (int j = 0; j < 8; j++) o[j] = (short)f2bf(bf2f((u16)v[j]) * s);
        *(short8*)&So[(size_t)(n0 + row) * 256 + c8] = o;
    }

    // TPSt: c-major scaled (each thread owns one c-row, 128B contiguous)
    u16* To = TPSt + (size_t)z * 262144 + (size_t)tid * 1024 + n0;
    #pragma unroll
    for (int jb = 0; jb < 8; jb++) {
        short8 o;
        #pragma unroll
        for (int j = 0; j < 8; j++) {
            int n = jb * 8 + j;
            o[j] = (short)f2bf(bf2f(ls[n][tid]) * dvs[n]);
        }
        *(short8*)&To[jb * 8] = o;
    }
}

// ---------------------------------------------------------------------------
// g_gemm: G[s][b] = WG_s @ XT^T + bg  (UNSCALED, single copy per stream)
// ---------------------------------------------------------------------------
__global__ __launch_bounds__(256) void g_gemm(
    const u16* __restrict__ XT, const u16* __restrict__ WG,
    const float* __restrict__ BG, u16* __restrict__ G)
{
    __shared__ alignas(16) u16 lsA[2 * 128 * 32];
    __shared__ alignas(16) u16 lsB[2 * 128 * 32];

    const int yb = blockIdx.x, zs = blockIdx.z;
    const int stream = zs >> 4;

    const u16* Ab = WG + stream * 32768;
    const u16* Bb = XT + (size_t)zs * 262144 + (size_t)(yb * 128) * 256;

    f32x4 acc[4][4] = {};
    gemm_core<128, 128, 2, 2>(Ab, nullptr, 256, 256, Bb, 256, 256, lsA, lsB, acc);

    const int lane = threadIdx.x & 63;
    const int wave = threadIdx.x >> 6;
    const int wr = wave >> 1, wc = wave & 1;
    const int rowb = (wr << 6) + ((lane >> 4) << 2);
    const int colb = yb * 128 + (wc << 6) + (lane & 15);
    u16* Gz = G + ((size_t)zs << 17);
    #pragma unroll
    for (int m = 0; m < 4; m++)
        #pragma unroll
        for (int r = 0; r < 4; r++) {
            int row = rowb + m * 16 + r;
            float bias = BG[stream * 128 + row];
            #pragma unroll
            for (int n = 0; n < 4; n++)
                Gz[((size_t)row << 10) + colb + n * 16] = f2bf(acc[m][n][r] + bias);
        }
}

// ---------------------------------------------------------------------------
// inner_splitk: M_split[c][j] = sum_{n in split} TPSt[z][c][n]*G'[j][n], c^128.
// B source: y==0 -> G[stream], y==1 -> G[stream 0] (the g_x cross rows).
// ---------------------------------------------------------------------------
__global__ __launch_bounds__(256) void inner_splitk(
    const u16* __restrict__ TPSt, const u16* __restrict__ G,
    u16* __restrict__ MX, u16* __restrict__ MB, u16* __restrict__ MD)
{
    __shared__ alignas(16) u16 lsA[2 * 128 * 32];
    __shared__ alignas(16) u16 lsB[2 * 128 * 32];

    const int bz = blockIdx.z;
    const int split = bz / 48, z = bz % 48;
    const int which = z >> 4, b = z & 15;
    if (which == 0 && blockIdx.y) return;
    u16* M = (which == 0) ? MX : (which == 1) ? MB : MD;
    const int JD  = (which == 0) ? 128 : 256;
    const int ldc = 2 * JD;
    const int srcz = blockIdx.y ? b : (which * 16 + b);

    const u16* Ab = TPSt + (size_t)z * 262144 + (size_t)(blockIdx.x * 128) * 1024 + split * 512;
    const u16* Bb = G + ((size_t)srcz << 17) + split * 512;

    f32x4 acc[4][4] = {};
    gemm_core<128, 128, 2, 2>(Ab, nullptr, 512, 1024, Bb, 1024, 512, lsA, lsB, acc);

    const int lane = threadIdx.x & 63;
    const int wave = threadIdx.x >> 6;
    const int wr = wave >> 1, wc = wave & 1;
    const int rowb = blockIdx.x * 128 + (wr << 6) + ((lane >> 4) << 2);
    const int colb = blockIdx.y * 128 + (wc << 6) + (lane & 15);
    u16* Cb = M + (size_t)b * (256 * ldc);
    #pragma unroll
    for (int m = 0; m < 4; m++)
        #pragma unroll
        for (int n = 0; n < 4; n++)
            #pragma unroll
            for (int r = 0; r < 4; r++) {
                int row = (rowb + m * 16 + r) ^ 128;
                int col = split * JD + colb + n * 16;
                Cb[(size_t)row * ldc + col] = f2bf(acc[m][n][r]);
            }
}

// ---------------------------------------------------------------------------
// fold: FF[o][c] = sum_{split,j} W_q[o][j] * M_split[c][coff+j]  (K=256)
// ---------------------------------------------------------------------------
__global__ __launch_bounds__(512) void fold_gemm(
    const u16* __restrict__ WF2, const u16* __restrict__ MX,
    const u16* __restrict__ MB, const u16* __restrict__ MD,
    u16* __restrict__ FF2)
{
    __shared__ alignas(16) u16 lsA[2 * 128 * 32];
    __shared__ alignas(16) u16 lsB[2 * 256 * 32];

    const int z = blockIdx.z, q = z >> 4, b = z & 15;
    const int pr = (q == 4) ? 2 : (q >> 1);
    const int side = (q == 1 || q == 3) ? 1 : 0;

    const u16* Ab = WF2 + q * 65536 + (size_t)(blockIdx.x * 128) * 256;

    f32x4 acc[4][4] = {};
    if (q == 4) {
        const u16* Bb = MX + (size_t)b * 65536;
        gemm_core<128, 256, 2, 4, false>(Ab, nullptr, 256, 256, Bb, 256, 256, lsA, lsB, acc);
    } else {
        const u16* Mp = (q == 1 || q == 2) ? MB : MD;
        const int coff = side ? 128 : 0;
        const u16* Bb = Mp + (size_t)b * 131072 + coff;
        gemm_core<128, 256, 2, 4, true>(Ab, nullptr, 256, 256, Bb, 512, 256, lsA, lsB, acc);
    }

    const int lane = threadIdx.x & 63;
    const int wave = threadIdx.x >> 6;
    const int wr = wave >> 2, wc = wave & 3;
    const int rowb = blockIdx.x * 128 + wr * 64 + ((lane >> 4) << 2);
    const int colb = wc * 64 + (lane & 15);
    u16* Cb = FF2 + (size_t)pr * 2097152 + (size_t)b * 131072;
    #pragma unroll
    for (int m = 0; m < 4; m++)
        #pragma unroll
        for (int n = 0; n < 4; n++)
            #pragma unroll
            for (int r = 0; r < 4; r++)
                Cb[(size_t)(rowb + m * 16 + r) * 512 + side * 256 + colb + n * 16]
                    = f2bf(acc[m][n][r]);
}

// ---------------------------------------------------------------------------
// outer: SINGLE dual-A K=512 core (rows pre-scaled via TPS), -> SALL + BN stats.
// zhi 0: s1 = TPSd@Fdd^T (+) TPSb@Fbx^T   (K-concat, B = FF2[0] straight)
// zhi 1: s2 = TPSb@Fbb^T (+) TPSd@Fdx^T
// zhi 2: xs = TPSx@Fxx^T                   (K=256)
// ---------------------------------------------------------------------------
__global__ __launch_bounds__(512) void outer_gemm(
    const u16* __restrict__ TPS, const u16* __restrict__ FF2,
    u16* __restrict__ SALL, float* __restrict__ BNA)
{
    __shared__ alignas(16) u16 lsA[2 * 128 * 32];
    __shared__ alignas(16) u16 lsB[2 * 256 * 32];

    const int z = blockIdx.z, zhi = z >> 4, b = z & 15;
    const int sa1[3] = {2, 1, 0}, sa2[3] = {1, 2, 0};
    const int K = (zhi == 2) ? 256 : 512;

    const u16* A1 = TPS + (size_t)(sa1[zhi] * 16 + b) * 262144 + (size_t)(blockIdx.x * 128) * 256;
    const u16* A2 = (zhi == 2) ? nullptr
                  : TPS + (size_t)(sa2[zhi] * 16 + b) * 262144 + (size_t)(blockIdx.x * 128) * 256;
    const u16* Bb = FF2 + (size_t)zhi * 2097152 + (size_t)b * 131072;

    f32x4 acc[4][4] = {};
    gemm_core<128, 256, 2, 4>(A1, A2, 256, 256, Bb, 512, K, lsA, lsB, acc);

    const int lane = threadIdx.x & 63;
    const int wave = threadIdx.x >> 6;
    const int wr = wave >> 2, wc = wave & 3;
    const int rowb = blockIdx.x * 128 + wr * 64 + ((lane >> 4) << 2);
    const int colb = wc * 64 + (lane & 15);

    u16* Cb = SALL + (size_t)b * 786432;
    float csum[4] = {}, csq[4] = {};
    #pragma unroll
    for (int m = 0; m < 4; m++)
        #pragma unroll
        for (int n = 0; n < 4; n++)
            #pragma unroll
            for (int r = 0; r < 4; r++) {
                float v = acc[m][n][r];
                Cb[(size_t)(rowb + m * 16 + r) * 768 + zhi * 256 + colb + n * 16] = f2bf(v);
                csum[n] += v;
                csq[n] += v * v;
            }
    if (zhi < 2) {
        #pragma unroll
        for (int n = 0; n < 4; n++) {
            float s = csum[n], q = csq[n];
            s += __shfl_xor(s, 16, 64); s += __shfl_xor(s, 32, 64);
            q += __shfl_xor(q, 16, 64); q += __shfl_xor(q, 32, 64);
            if (lane < 16) {
                atomicAdd(&BNA[zhi * 512 + colb + n * 16], s);
                atomicAdd(&BNA[zhi * 512 + 256 + colb + n * 16], q);
            }
        }
    }
}

// ---------------------------------------------------------------------------
// bnscale: WoutS = [Wout*sc1 | Wout*sc2 | Wout], BIAS2 = bout + Wout@(sh1+sh2+bwx)
// ---------------------------------------------------------------------------
__global__ __launch_bounds__(256) void bnscale(
    const float* __restrict__ Wout, const float* __restrict__ g1, const float* __restrict__ be1,
    const float* __restrict__ g2, const float* __restrict__ be2,
    const float* __restrict__ bwx, const float* __restrict__ bout,
    const float* __restrict__ BNA, u16* __restrict__ WoutS, float* __restrict__ BIAS2)
{
    int o = blockIdx.x, c = threadIdx.x;
    const float inv = 1.0f / 16384.0f;
    float m1 = BNA[c] * inv;
    float v1 = BNA[256 + c] * inv - m1 * m1;
    float sc1 = g1[c] * rsqrtf(v1 + 1e-5f), sh1 = be1[c] - m1 * sc1;
    float m2 = BNA[512 + c] * inv;
    float v2 = BNA[768 + c] * inv - m2 * m2;
    float sc2 = g2[c] * rsqrtf(v2 + 1e-5f), sh2 = be2[c] - m2 * sc2;
    float wv = Wout[o * 256 + c];
    WoutS[o * 768 + c]       = f2bf(wv * sc1);
    WoutS[o * 768 + 256 + c] = f2bf(wv * sc2);
    WoutS[o * 768 + 512 + c] = f2bf(wv);
    __shared__ float red[256];
    red[c] = wv * (sh1 + sh2 + bwx[c]);
    __syncthreads();
    for (int s = 128; s; s >>= 1) { if (c < s) red[c] += red[c + s]; __syncthreads(); }
    if (c == 0) BIAS2[o] = red[0] + bout[o];
}

// ---------------------------------------------------------------------------
// final_split: split-K=2 over K=768; out (pre-initialized to x by prep)
// accumulated via fp32 atomicAdd. grid (2,8,32), 256 thr.
// ---------------------------------------------------------------------------
__global__ __launch_bounds__(256) void final_split(
    const u16* __restrict__ WoutS, const u16* __restrict__ SALL,
    const float* __restrict__ BIAS2, float* __restrict__ out)
{
    __shared__ alignas(16) u16 lsA[2 * 128 * 32];
    __shared__ alignas(16) u16 lsB[2 * 128 * 32];

    const int split = blockIdx.z >> 4, b = blockIdx.z & 15;
    const int xb = blockIdx.x, yb = blockIdx.y;

    const u16* Ab = WoutS + (size_t)(xb * 128) * 768 + split * 384;
    const u16* Bb = SALL + (size_t)b * 786432 + (size_t)(yb * 128) * 768 + split * 384;

    f32x4 acc[4][4] = {};
    gemm_core<128, 128, 2, 2>(Ab, nullptr, 384, 768, Bb, 768, 384, lsA, lsB, acc);

    const int lane = threadIdx.x & 63;
    const int wave = threadIdx.x >> 6;
    const int wr = wave >> 1, wc = wave & 1;
    const int rowb = xb * 128 + (wr << 6) + ((lane >> 4) << 2);
    const int colb = yb * 128 + (wc << 6) + (lane & 15);
    #pragma unroll
    for (int m = 0; m < 4; m++)
        #pragma unroll
        for (int n = 0; n < 4; n++)
            #pragma unroll
            for (int r = 0; r < 4; r++) {
                int row = rowb + m * 16 + r;
                int col = colb + n * 16;
                float v = acc[m][n][r];
                if (split == 0) v += BIAS2[row];
                atomicAdd(&out[(size_t)b * 262144 + (size_t)row * 1024 + col], v);
            }
}

// ---------------------------------------------------------------------------
// prep_transpose: vectorized 64x64 transpose tiles (float4 in, short8 out).
// which==0 tiles also copy x -> out (residual init for split-K final).
// z==48 block: weight prep + zeroing of atomics (CS|BNA = 13312 floats).
// ---------------------------------------------------------------------------
__global__ __launch_bounds__(256) void prep_transpose(
    const float* __restrict__ x, const float* __restrict__ ob,
    const float* __restrict__ od, u16* __restrict__ xt,
    const float* Wt, const float* Wp,
    const float* Wgx, const float* Wgb, const float* Wgd,
    const float* bgx, const float* bgb, const float* bgd,
    const float* Wwd, const float* Wwxb, const float* Wwb,
    const float* Wwxd, const float* Wwx,
    u16* wtp, u16* wg, u16* wf2, float* bg,
    float* __restrict__ ZZ, float* __restrict__ outp)
{
    const int tid = threadIdx.x;
    if (blockIdx.z == 48) {
        int base = (blockIdx.y * 16 + blockIdx.x) * 1024;
        #pragma unroll
        for (int l = 0; l < 4; l++) {
            int t = base + l * 256 + tid;
            wtp[t] = f2bf(t < 32768 ? Wt[t] : Wp[t - 32768]);
            if (t < 32768) {
                wg[t] = f2bf(Wgx[t]); wg[32768 + t] = f2bf(Wgb[t]); wg[65536 + t] = f2bf(Wgd[t]);
            }
            {
                int o = t >> 8, k = t & 255, j = k & 127;
                const float* Wq[5] = {Wwd, Wwxb, Wwb, Wwxd, Wwx};
                #pragma unroll
                for (int q = 0; q < 5; q++)
                    wf2[q * 65536 + t] = f2bf(0.5f * Wq[q][o * 128 + j]);
            }
            if (t < 384) bg[t] = (t < 128) ? bgx[t] : (t < 256) ? bgb[t - 128] : bgd[t - 256];
            if (t < 13312) ZZ[t] = 0.0f;
        }
        return;
    }
    __shared__ float ls[64][68];
    const int z = blockIdx.z, which = z >> 4, b = z & 15;
    const float* src = (which == 0) ? x : (which == 1) ? ob : od;
    const float* s = src + (size_t)b * cC * cN;
    u16* dst = xt + (size_t)z * (cN * cC);
    float* ox = outp + (size_t)b * (cC * cN);
    const int n0 = blockIdx.x << 6, c0 = blockIdx.y << 6;

    const int cl0 = tid >> 4, n4 = (tid & 15) << 2;
    #pragma unroll
    for (int p = 0; p < 4; p++) {
        int cl = cl0 + (p << 4);
        f32x4 v = *(const f32x4*)&s[(size_t)(c0 + cl) * cN + n0 + n4];
        if (which == 0) *(f32x4*)&ox[(size_t)(c0 + cl) * cN + n0 + n4] = v;
        ls[cl][n4] = v[0]; ls[cl][n4 + 1] = v[1]; ls[cl][n4 + 2] = v[2]; ls[cl][n4 + 3] = v[3];
    }
    __syncthreads();
    const int nl0 = tid >> 3, c8 = (tid & 7) << 3;
    #pragma unroll
    for (int q = 0; q < 2; q++) {
        int nl = nl0 + (q << 5);
        short8 o;
        #pragma unroll
        for (int j = 0; j < 8; j++) o[j] = (short)f2bf(ls[c8 + j][nl]);
        *(short8*)&dst[(size_t)(n0 + nl) * 256 + c0 + c8] = o;
    }
}

// ---------------------------------------------------------------------------
extern "C" void kernel_launch(void* const* d_in, const int* in_sizes, int n_in,
                              void* d_out, int out_size, void* d_ws, size_t ws_size,
                              hipStream_t stream)
{
    const float* x    = (const float*)d_in[0];
    const float* ob   = (const float*)d_in[1];
    const float* od   = (const float*)d_in[2];
    const float* Wt   = (const float*)d_in[3];
    const float* Wp   = (const float*)d_in[4];
    const float* Wgx  = (const float*)d_in[5];
    const float* bgx  = (const float*)d_in[6];
    const float* Wgb  = (const float*)d_in[7];
    const float* bgb  = (const float*)d_in[8];
    const float* Wgd  = (const float*)d_in[9];
    const float* bgd  = (const float*)d_in[10];
    const float* Wwx  = (const float*)d_in[11];
    const float* bwx  = (const float*)d_in[12];
    const float* Wwb  = (const float*)d_in[13];
    const float* Wwd  = (const float*)d_in[15];
    const float* Wwxb = (const float*)d_in[17];
    const float* Wwxd = (const float*)d_in[19];
    const float* g1   = (const float*)d_in[21];
    const float* be1  = (const float*)d_in[22];
    const float* g2   = (const float*)d_in[23];
    const float* be2  = (const float*)d_in[24];
    const float* Wout = (const float*)d_in[25];
    const float* bout = (const float*)d_in[26];
    float* out = (float*)d_out;

    char* w = (char*)d_ws;
    u16*   XT    = (u16*)(w);                    // [3][16][1024][256]  25165824 B
    u16*   TP    = (u16*)(w + 25165824);         // [3][16][1024][256]  25165824 B (raw; reused as SALL)
    u16*   TPS   = (u16*)(w + 50331648);         // [3][16][1024][256]  25165824 B (scaled, n-major)
    u16*   TPSt  = (u16*)(w + 75497472);         // [3][16][256][1024]  25165824 B (scaled, c-major)
    u16*   G     = (u16*)(w + 100663296);        // [3][16][128][1024]  12582912 B (unscaled)
    u16*   MX    = (u16*)(w + 113246208);        // [16][256][256]      2097152 B
    u16*   MB    = (u16*)(w + 115343360);        // [16][256][512]      4194304 B
    u16*   MD    = (u16*)(w + 119537664);        // [16][256][512]      4194304 B
    u16*   FF2   = (u16*)(w + 123731968);        // [3][16][256][512]   12582912 B
    u16*   WTP   = (u16*)(w + 136314880);        // 131072 B
    u16*   WG    = (u16*)(w + 136445952);        // 196608 B
    u16*   WF2   = (u16*)(w + 136642560);        // [5][256][256]       655360 B
    u16*   WoutS = (u16*)(w + 137297920);        // [256][768]          393216 B
    float* BGf   = (float*)(w + 137691136);      // 2048 B
    float* BIAS2 = (float*)(w + 137693184);      // 4096 B
    float* ZZ    = (float*)(w + 137697280);      // 53248 B (CS | BNA, atomics)

    float* CS   = ZZ;                 // [48][256]
    float* BNA  = ZZ + 12288;         // [1024]
    u16*   SALL = TP;                 // [16][1024][768]; TP dead after tpt2

    // 1. prep + transpose + out=x + zero atomics region
    prep_transpose<<<dim3(16, 4, 49), 256, 0, stream>>>(
        x, ob, od, XT, Wt, Wp, Wgx, Wgb, Wgd, bgx, bgb, bgd,
        Wwd, Wwxb, Wwb, Wwxd, Wwx, WTP, WG, WF2, BGf, ZZ, out);

    // 2. TP = relu(XT @ WTP^T) + fused column sums -> CS
    tp_gemm<<<dim3(8, 1, 48), 512, 0, stream>>>(XT, WTP, TP, CS);

    // 3. d[n] in-block -> scaled TPS (n-major) + TPSt (c-major)
    tpt2<<<dim3(16, 1, 48), 256, 0, stream>>>(TP, CS, TPS, TPSt);

    // 4. unscaled G (no dinv dependency)
    g_gemm<<<dim3(8, 1, 48), 256, 0, stream>>>(XT, WG, BGf, G);

    // 5. inner factors, split-K=2 (TPSt scaled x G unscaled)
    inner_splitk<<<dim3(2, 2, 96), 256, 0, stream>>>(TPSt, G, MX, MB, MD);

    // 6. folds -> FF2
    fold_gemm<<<dim3(2, 1, 80), 512, 0, stream>>>(WF2, MX, MB, MD, FF2);

    // 7. outers (single dual-A K=512 core) -> SALL + BN stats
    outer_gemm<<<dim3(8, 1, 48), 512, 0, stream>>>(TPS, FF2, SALL, BNA);

    // 8. BN folded into Wout
    bnscale<<<dim3(256), 256, 0, stream>>>(Wout, g1, be1, g2, be2, bwx, bout,
                                           BNA, WoutS, BIAS2);

    // 9. out += WoutS @ SALL^T + BIAS2   (split-K=2, atomic fp32)
    final_split<<<dim3(2, 8, 32), 256, 0, stream>>>(WoutS, SALL, BIAS2, out);
}

// Round 12
// 142.156 us; speedup vs baseline: 1.1909x; 1.1909x over previous
//
#include <hip/hip_runtime.h>

#define GAS __attribute__((address_space(1)))
#define LAS __attribute__((address_space(3)))

typedef __attribute__((ext_vector_type(8))) short short8;
typedef __attribute__((ext_vector_type(4))) float f32x4;
typedef unsigned short u16;

constexpr int cB = 16, cC = 256, cIC = 128, cN = 1024;

__device__ __forceinline__ u16 f2bf(float v) {
    unsigned u = __builtin_bit_cast(unsigned, v);
    return (u16)((u + 0x7fffu + ((u >> 16) & 1u)) >> 16);
}
__device__ __forceinline__ float bf2f(u16 v) {
    unsigned u = ((unsigned)v) << 16;
    return __builtin_bit_cast(float, u);
}
__device__ __forceinline__ float rsz(float d) {
    return (d != 0.0f) ? rsqrtf(d) : 0.0f;
}

template<int N> __device__ __forceinline__ void wait_vmcnt() {
    if constexpr (N == 0) asm volatile("s_waitcnt vmcnt(0)" ::: "memory");
    else if constexpr (N == 1) asm volatile("s_waitcnt vmcnt(1)" ::: "memory");
    else if constexpr (N == 2) asm volatile("s_waitcnt vmcnt(2)" ::: "memory");
    else if constexpr (N == 3) asm volatile("s_waitcnt vmcnt(3)" ::: "memory");
    else if constexpr (N == 4) asm volatile("s_waitcnt vmcnt(4)" ::: "memory");
    else if constexpr (N == 5) asm volatile("s_waitcnt vmcnt(5)" ::: "memory");
    else if constexpr (N == 6) asm volatile("s_waitcnt vmcnt(6)" ::: "memory");
    else if constexpr (N == 8) asm volatile("s_waitcnt vmcnt(8)" ::: "memory");
}

// ---------------------------------------------------------------------------
// Double-buffered prefetch GEMM core with LDS XOR-swizzle (2-way max).
// C[m,n] = sum_k A[m,k]*B[n,k]  (both K-major).
// Dual-A: for kk >= ksplit reads Ab2 + (kk - ksplit).
// BREMAP: B column for k-chunk kk is ((kk>>7)<<8)+(kk&127).
// ---------------------------------------------------------------------------
template<int BM, int BN, int WR, int WC, bool BREMAP = false>
__device__ __forceinline__ void gemm_core(
    const u16* __restrict__ Ab, const u16* __restrict__ Ab2, int ksplit, int lda,
    const u16* __restrict__ Bb, int ldb, int K,
    u16* lsA, u16* lsB,
    f32x4 (&acc)[BM/(WR*16)][BN/(WC*16)])
{
    constexpr int THREADS = WR * WC * 64;
    constexpr int MR = BM / (WR * 16), NR = BN / (WC * 16);
    constexpr int ACH = (BM * 64) / (THREADS * 16);
    constexpr int BCH = (BN * 64) / (THREADS * 16);
    constexpr int RPC = THREADS / 4;
    constexpr int ISSUES = ACH + BCH;

    const int tid  = threadIdx.x;
    const int lane = tid & 63;
    const int wave = tid >> 6;
    const int wr = wave / WC, wc = wave % WC;
    const int r0 = tid >> 2, slot = tid & 3;

    auto stage = [&](int buf, int kk) {
        const u16* Ak = (Ab2 != nullptr && kk >= ksplit) ? (Ab2 + (kk - ksplit)) : (Ab + kk);
        const u16* Bk = Bb + (BREMAP ? (((kk >> 7) << 8) + (kk & 127)) : kk);
        #pragma unroll
        for (int c = 0; c < ACH; c++) {
            int row = c * RPC + r0;
            int sk = (slot ^ ((row >> 1) & 3)) << 3;
            __builtin_amdgcn_global_load_lds((GAS void*)(Ak + (size_t)row * lda + sk),
                (LAS void*)(lsA + buf * (BM * 32) + c * (THREADS * 8) + (wave << 9)), 16, 0, 0);
        }
        #pragma unroll
        for (int c = 0; c < BCH; c++) {
            int row = c * RPC + r0;
            int sk = (slot ^ ((row >> 1) & 3)) << 3;
            __builtin_amdgcn_global_load_lds((GAS void*)(Bk + (size_t)row * ldb + sk),
                (LAS void*)(lsB + buf * (BN * 32) + c * (THREADS * 8) + (wave << 9)), 16, 0, 0);
        }
    };

    stage(0, 0);
    const int nt = K >> 5;
    for (int t = 0; t < nt; t++) {
        const int cur = t & 1;
        if (t + 1 < nt) { stage(cur ^ 1, (t + 1) << 5); wait_vmcnt<ISSUES>(); }
        else            wait_vmcnt<0>();
        __builtin_amdgcn_s_barrier();
        asm volatile("" ::: "memory");

        const u16* la = lsA + cur * (BM * 32);
        const u16* lb = lsB + cur * (BN * 32);
        short8 af[MR], bf[NR];
        #pragma unroll
        for (int m = 0; m < MR; m++) {
            int row = wr * (BM / WR) + (m << 4) + (lane & 15);
            af[m] = *(const short8*)&la[(row << 5) + (((lane >> 4) ^ ((row >> 1) & 3)) << 3)];
        }
        #pragma unroll
        for (int n = 0; n < NR; n++) {
            int row = wc * (BN / WC) + (n << 4) + (lane & 15);
            bf[n] = *(const short8*)&lb[(row << 5) + (((lane >> 4) ^ ((row >> 1) & 3)) << 3)];
        }
        #pragma unroll
        for (int m = 0; m < MR; m++)
            #pragma unroll
            for (int n = 0; n < NR; n++)
                acc[m][n] = __builtin_amdgcn_mfma_f32_16x16x32_bf16(af[m], bf[n], acc[m][n], 0, 0, 0);

        asm volatile("s_waitcnt lgkmcnt(0)" ::: "memory");
        __builtin_amdgcn_sched_barrier(0);
        __builtin_amdgcn_s_barrier();
    }
}

// ---------------------------------------------------------------------------
// Generic GEMM wrapper (used by the final conv). z: zlo=z&15, zhi=z>>4.
// ---------------------------------------------------------------------------
template<int BM, int BN, int WR, int WC, bool RELU, bool OBF16, bool RBIAS, bool RESID>
__global__ __launch_bounds__(WR*WC*64) void gemm_bt(
    const u16* __restrict__ A, long long sA, long long sA2, int lda,
    const u16* __restrict__ B, long long sB, long long sB2, int ldb,
    void* __restrict__ C, long long sC, long long sC2, int ldc,
    int K,
    const float* __restrict__ bias, int sb2,
    const float* __restrict__ resid, long long sR)
{
    __shared__ alignas(16) u16 lsA[2 * BM * 32];
    __shared__ alignas(16) u16 lsB[2 * BN * 32];

    const int lane = threadIdx.x & 63;
    const int wave = threadIdx.x >> 6;
    const int wr = wave / WC, wc = wave % WC;
    const int zlo = blockIdx.z & 15, zhi = blockIdx.z >> 4;

    const u16* Ab = A + zlo * sA + zhi * sA2 + (size_t)(blockIdx.x * BM) * lda;
    const u16* Bb = B + zlo * sB + zhi * sB2 + (size_t)(blockIdx.y * BN) * ldb;

    f32x4 acc[BM/(WR*16)][BN/(WC*16)] = {};
    gemm_core<BM, BN, WR, WC>(Ab, nullptr, K, lda, Bb, ldb, K, lsA, lsB, acc);

    const int rowb = blockIdx.x * BM + wr * (BM / WR) + ((lane >> 4) << 2);
    const int colb = blockIdx.y * BN + wc * (BN / WC) + (lane & 15);
    const long long cbase = zlo * sC + zhi * sC2;
    #pragma unroll
    for (int m = 0; m < BM/(WR*16); m++) {
        #pragma unroll
        for (int n = 0; n < BN/(WC*16); n++) {
            #pragma unroll
            for (int r = 0; r < 4; r++) {
                int row = rowb + m * 16 + r;
                int col = colb + n * 16;
                float v = acc[m][n][r];
                if (RBIAS) v += bias[zhi * sb2 + row];
                if (RESID) v += resid[zlo * sR + (size_t)row * ldc + col];
                if (RELU)  v = fmaxf(v, 0.0f);
                if (OBF16) ((u16*)C)[cbase + (size_t)row * ldc + col] = f2bf(v);
                else       ((float*)C)[cbase + (size_t)row * ldc + col] = v;
            }
        }
    }
}

// ---------------------------------------------------------------------------
// tp_gemm: TP[z][n][c] = relu(XT @ WTP^T) with fused column sums (over n)
// -> CS[z][c]. 384 blocks of 512 threads, tile 128x256.
// ---------------------------------------------------------------------------
__global__ __launch_bounds__(512) void tp_gemm(
    const u16* __restrict__ XT, const u16* __restrict__ WTP,
    u16* __restrict__ TP, float* __restrict__ CS)
{
    __shared__ alignas(16) u16 lsA[2 * 128 * 32];
    __shared__ alignas(16) u16 lsB[2 * 256 * 32];

    const int nx = blockIdx.x, z = blockIdx.z;
    const u16* Ab = XT + (size_t)z * 262144 + (size_t)(nx * 128) * 256;

    f32x4 acc[4][4] = {};
    gemm_core<128, 256, 2, 4>(Ab, nullptr, 256, 256, WTP, 256, 256, lsA, lsB, acc);

    const int lane = threadIdx.x & 63;
    const int wave = threadIdx.x >> 6;
    const int wr = wave >> 2, wc = wave & 3;
    const int rowb = nx * 128 + wr * 64 + ((lane >> 4) << 2);
    const int colb = wc * 64 + (lane & 15);
    u16* Cb = TP + (size_t)z * 262144;

    float cp[4] = {};
    #pragma unroll
    for (int m = 0; m < 4; m++)
        #pragma unroll
        for (int n = 0; n < 4; n++)
            #pragma unroll
            for (int r = 0; r < 4; r++) {
                float v = fmaxf(acc[m][n][r], 0.0f);
                Cb[(size_t)(rowb + m * 16 + r) * 256 + colb + n * 16] = f2bf(v);
                cp[n] += v;
            }
    #pragma unroll
    for (int n = 0; n < 4; n++) {
        float v = cp[n];
        v += __shfl_xor(v, 16, 64);
        v += __shfl_xor(v, 32, 64);
        if (lane < 16)
            atomicAdd(&CS[z * 256 + colb + n * 16], v);
    }
}

// ---------------------------------------------------------------------------
// tpt2: per block, 64 n-rows x all 256 c of TP. Computes d[n] fully in-block
// (d[n] = sum_c TP[n][c] * 0.5*CS[c^128]), then writes BOTH dv-scaled layouts:
//   TPS [z][n][c] (n-major) and TPSt [z][c][n] (c-major).
// grid (16,1,48), 256 threads. DINV never materialized.
// ---------------------------------------------------------------------------
__global__ __launch_bounds__(256) void tpt2(
    const u16* __restrict__ TP, const float* __restrict__ CS,
    u16* __restrict__ TPS, u16* __restrict__ TPSt)
{
    __shared__ u16 ls[64][264];     // row stride 264 (16B-aligned rows)
    __shared__ float ws[256];
    __shared__ float pd[64][4];
    __shared__ float dvs[64];

    const int z = blockIdx.z;
    const int n0 = blockIdx.x << 6;
    const int tid = threadIdx.x;

    ws[tid] = 0.5f * CS[z * 256 + (tid ^ 128)];

    const u16* src = TP + (size_t)z * 262144;
    #pragma unroll
    for (int k = 0; k < 8; k++) {
        int chunk = k * 256 + tid;
        int row = chunk >> 5, c8 = (chunk & 31) << 3;
        *(short8*)&ls[row][c8] = *(const short8*)&src[(size_t)(n0 + row) * 256 + c8];
    }
    __syncthreads();

    {
        const int row = tid >> 2, q = tid & 3;
        float a = 0;
        #pragma unroll 16
        for (int i = 0; i < 64; i++) {
            int c = q * 64 + i;
            a += bf2f(ls[row][c]) * ws[c];
        }
        pd[row][q] = a;
    }
    __syncthreads();
    if (tid < 64) {
        float d = pd[tid][0] + pd[tid][1] + pd[tid][2] + pd[tid][3];
        dvs[tid] = rsz(d);
    }
    __syncthreads();

    // TPS: n-major scaled (coalesced rows)
    u16* So = TPS + (size_t)z * 262144;
    #pragma unroll
    for (int k = 0; k < 8; k++) {
        int chunk = k * 256 + tid;
        int row = chunk >> 5, c8 = (chunk & 31) << 3;
        short8 v = *(const short8*)&ls[row][c8];
        float s = dvs[row];
        short8 o;
        #pragma unroll
        for (int j = 0; j < 8; j++) o[j] = (short)f2bf(bf2f((u16)v[j]) * s);
        *(short8*)&So[(size_t)(n0 + row) * 256 + c8] = o;
    }

    // TPSt: c-major scaled (each thread owns one c-row, 128B contiguous)
    u16* To = TPSt + (size_t)z * 262144 + (size_t)tid * 1024 + n0;
    #pragma unroll
    for (int jb = 0; jb < 8; jb++) {
        short8 o;
        #pragma unroll
        for (int j = 0; j < 8; j++) {
            int n = jb * 8 + j;
            o[j] = (short)f2bf(bf2f(ls[n][tid]) * dvs[n]);
        }
        *(short8*)&To[jb * 8] = o;
    }
}

// ---------------------------------------------------------------------------
// g_gemm: G[s][b] = WG_s @ XT^T + bg  (UNSCALED, single copy per stream)
// ---------------------------------------------------------------------------
__global__ __launch_bounds__(256) void g_gemm(
    const u16* __restrict__ XT, const u16* __restrict__ WG,
    const float* __restrict__ BG, u16* __restrict__ G)
{
    __shared__ alignas(16) u16 lsA[2 * 128 * 32];
    __shared__ alignas(16) u16 lsB[2 * 128 * 32];

    const int yb = blockIdx.x, zs = blockIdx.z;
    const int stream = zs >> 4;

    const u16* Ab = WG + stream * 32768;
    const u16* Bb = XT + (size_t)zs * 262144 + (size_t)(yb * 128) * 256;

    f32x4 acc[4][4] = {};
    gemm_core<128, 128, 2, 2>(Ab, nullptr, 256, 256, Bb, 256, 256, lsA, lsB, acc);

    const int lane = threadIdx.x & 63;
    const int wave = threadIdx.x >> 6;
    const int wr = wave >> 1, wc = wave & 1;
    const int rowb = (wr << 6) + ((lane >> 4) << 2);
    const int colb = yb * 128 + (wc << 6) + (lane & 15);
    u16* Gz = G + ((size_t)zs << 17);
    #pragma unroll
    for (int m = 0; m < 4; m++)
        #pragma unroll
        for (int r = 0; r < 4; r++) {
            int row = rowb + m * 16 + r;
            float bias = BG[stream * 128 + row];
            #pragma unroll
            for (int n = 0; n < 4; n++)
                Gz[((size_t)row << 10) + colb + n * 16] = f2bf(acc[m][n][r] + bias);
        }
}

// ---------------------------------------------------------------------------
// inner_splitk: M_split[c][j] = sum_{n in split} TPSt[z][c][n]*G'[j][n], c^128.
// B source: y==0 -> G[stream], y==1 -> G[stream 0] (the g_x cross rows).
// ---------------------------------------------------------------------------
__global__ __launch_bounds__(256) void inner_splitk(
    const u16* __restrict__ TPSt, const u16* __restrict__ G,
    u16* __restrict__ MX, u16* __restrict__ MB, u16* __restrict__ MD)
{
    __shared__ alignas(16) u16 lsA[2 * 128 * 32];
    __shared__ alignas(16) u16 lsB[2 * 128 * 32];

    const int bz = blockIdx.z;
    const int split = bz / 48, z = bz % 48;
    const int which = z >> 4, b = z & 15;
    if (which == 0 && blockIdx.y) return;
    u16* M = (which == 0) ? MX : (which == 1) ? MB : MD;
    const int JD  = (which == 0) ? 128 : 256;
    const int ldc = 2 * JD;
    const int srcz = blockIdx.y ? b : (which * 16 + b);

    const u16* Ab = TPSt + (size_t)z * 262144 + (size_t)(blockIdx.x * 128) * 1024 + split * 512;
    const u16* Bb = G + ((size_t)srcz << 17) + split * 512;

    f32x4 acc[4][4] = {};
    gemm_core<128, 128, 2, 2>(Ab, nullptr, 512, 1024, Bb, 1024, 512, lsA, lsB, acc);

    const int lane = threadIdx.x & 63;
    const int wave = threadIdx.x >> 6;
    const int wr = wave >> 1, wc = wave & 1;
    const int rowb = blockIdx.x * 128 + (wr << 6) + ((lane >> 4) << 2);
    const int colb = blockIdx.y * 128 + (wc << 6) + (lane & 15);
    u16* Cb = M + (size_t)b * (256 * ldc);
    #pragma unroll
    for (int m = 0; m < 4; m++)
        #pragma unroll
        for (int n = 0; n < 4; n++)
            #pragma unroll
            for (int r = 0; r < 4; r++) {
                int row = (rowb + m * 16 + r) ^ 128;
                int col = split * JD + colb + n * 16;
                Cb[(size_t)row * ldc + col] = f2bf(acc[m][n][r]);
            }
}

// ---------------------------------------------------------------------------
// fold: FF[o][c] = sum_{split,j} W_q[o][j] * M_split[c][coff+j]  (K=256)
// ---------------------------------------------------------------------------
__global__ __launch_bounds__(512) void fold_gemm(
    const u16* __restrict__ WF2, const u16* __restrict__ MX,
    const u16* __restrict__ MB, const u16* __restrict__ MD,
    u16* __restrict__ FF2)
{
    __shared__ alignas(16) u16 lsA[2 * 128 * 32];
    __shared__ alignas(16) u16 lsB[2 * 256 * 32];

    const int z = blockIdx.z, q = z >> 4, b = z & 15;
    const int pr = (q == 4) ? 2 : (q >> 1);
    const int side = (q == 1 || q == 3) ? 1 : 0;

    const u16* Ab = WF2 + q * 65536 + (size_t)(blockIdx.x * 128) * 256;

    f32x4 acc[4][4] = {};
    if (q == 4) {
        const u16* Bb = MX + (size_t)b * 65536;
        gemm_core<128, 256, 2, 4, false>(Ab, nullptr, 256, 256, Bb, 256, 256, lsA, lsB, acc);
    } else {
        const u16* Mp = (q == 1 || q == 2) ? MB : MD;
        const int coff = side ? 128 : 0;
        const u16* Bb = Mp + (size_t)b * 131072 + coff;
        gemm_core<128, 256, 2, 4, true>(Ab, nullptr, 256, 256, Bb, 512, 256, lsA, lsB, acc);
    }

    const int lane = threadIdx.x & 63;
    const int wave = threadIdx.x >> 6;
    const int wr = wave >> 2, wc = wave & 3;
    const int rowb = blockIdx.x * 128 + wr * 64 + ((lane >> 4) << 2);
    const int colb = wc * 64 + (lane & 15);
    u16* Cb = FF2 + (size_t)pr * 2097152 + (size_t)b * 131072;
    #pragma unroll
    for (int m = 0; m < 4; m++)
        #pragma unroll
        for (int n = 0; n < 4; n++)
            #pragma unroll
            for (int r = 0; r < 4; r++)
                Cb[(size_t)(rowb + m * 16 + r) * 512 + side * 256 + colb + n * 16]
                    = f2bf(acc[m][n][r]);
}

// ---------------------------------------------------------------------------
// outer: SINGLE dual-A K=512 core (rows pre-scaled via TPS), -> SALL + BN stats.
// zhi 0: s1 = TPSd@Fdd^T (+) TPSb@Fbx^T   (K-concat, B = FF2[0] straight)
// zhi 1: s2 = TPSb@Fbb^T (+) TPSd@Fdx^T
// zhi 2: xs = TPSx@Fxx^T                   (K=256)
// ---------------------------------------------------------------------------
__global__ __launch_bounds__(512) void outer_gemm(
    const u16* __restrict__ TPS, const u16* __restrict__ FF2,
    u16* __restrict__ SALL, float* __restrict__ BNA)
{
    __shared__ alignas(16) u16 lsA[2 * 128 * 32];
    __shared__ alignas(16) u16 lsB[2 * 256 * 32];

    const int z = blockIdx.z, zhi = z >> 4, b = z & 15;
    const int sa1[3] = {2, 1, 0}, sa2[3] = {1, 2, 0};
    const int K = (zhi == 2) ? 256 : 512;

    const u16* A1 = TPS + (size_t)(sa1[zhi] * 16 + b) * 262144 + (size_t)(blockIdx.x * 128) * 256;
    const u16* A2 = (zhi == 2) ? nullptr
                  : TPS + (size_t)(sa2[zhi] * 16 + b) * 262144 + (size_t)(blockIdx.x * 128) * 256;
    const u16* Bb = FF2 + (size_t)zhi * 2097152 + (size_t)b * 131072;

    f32x4 acc[4][4] = {};
    gemm_core<128, 256, 2, 4>(A1, A2, 256, 256, Bb, 512, K, lsA, lsB, acc);

    const int lane = threadIdx.x & 63;
    const int wave = threadIdx.x >> 6;
    const int wr = wave >> 2, wc = wave & 3;
    const int rowb = blockIdx.x * 128 + wr * 64 + ((lane >> 4) << 2);
    const int colb = wc * 64 + (lane & 15);

    u16* Cb = SALL + (size_t)b * 786432;
    float csum[4] = {}, csq[4] = {};
    #pragma unroll
    for (int m = 0; m < 4; m++)
        #pragma unroll
        for (int n = 0; n < 4; n++)
            #pragma unroll
            for (int r = 0; r < 4; r++) {
                float v = acc[m][n][r];
                Cb[(size_t)(rowb + m * 16 + r) * 768 + zhi * 256 + colb + n * 16] = f2bf(v);
                csum[n] += v;
                csq[n] += v * v;
            }
    if (zhi < 2) {
        #pragma unroll
        for (int n = 0; n < 4; n++) {
            float s = csum[n], q = csq[n];
            s += __shfl_xor(s, 16, 64); s += __shfl_xor(s, 32, 64);
            q += __shfl_xor(q, 16, 64); q += __shfl_xor(q, 32, 64);
            if (lane < 16) {
                atomicAdd(&BNA[zhi * 512 + colb + n * 16], s);
                atomicAdd(&BNA[zhi * 512 + 256 + colb + n * 16], q);
            }
        }
    }
}

// ---------------------------------------------------------------------------
// bnscale: WoutS = [Wout*sc1 | Wout*sc2 | Wout], BIAS2 = bout + Wout@(sh1+sh2+bwx)
// ---------------------------------------------------------------------------
__global__ __launch_bounds__(256) void bnscale(
    const float* __restrict__ Wout, const float* __restrict__ g1, const float* __restrict__ be1,
    const float* __restrict__ g2, const float* __restrict__ be2,
    const float* __restrict__ bwx, const float* __restrict__ bout,
    const float* __restrict__ BNA, u16* __restrict__ WoutS, float* __restrict__ BIAS2)
{
    int o = blockIdx.x, c = threadIdx.x;
    const float inv = 1.0f / 16384.0f;
    float m1 = BNA[c] * inv;
    float v1 = BNA[256 + c] * inv - m1 * m1;
    float sc1 = g1[c] * rsqrtf(v1 + 1e-5f), sh1 = be1[c] - m1 * sc1;
    float m2 = BNA[512 + c] * inv;
    float v2 = BNA[768 + c] * inv - m2 * m2;
    float sc2 = g2[c] * rsqrtf(v2 + 1e-5f), sh2 = be2[c] - m2 * sc2;
    float wv = Wout[o * 256 + c];
    WoutS[o * 768 + c]       = f2bf(wv * sc1);
    WoutS[o * 768 + 256 + c] = f2bf(wv * sc2);
    WoutS[o * 768 + 512 + c] = f2bf(wv);
    __shared__ float red[256];
    red[c] = wv * (sh1 + sh2 + bwx[c]);
    __syncthreads();
    for (int s = 128; s; s >>= 1) { if (c < s) red[c] += red[c + s]; __syncthreads(); }
    if (c == 0) BIAS2[o] = red[0] + bout[o];
}

// ---------------------------------------------------------------------------
// prep_transpose: vectorized 64x64 transpose tiles (float4 in, short8 out).
// z==48 block: weight prep + zeroing of atomics (CS|BNA = 13312 floats).
// ---------------------------------------------------------------------------
__global__ __launch_bounds__(256) void prep_transpose(
    const float* __restrict__ x, const float* __restrict__ ob,
    const float* __restrict__ od, u16* __restrict__ xt,
    const float* Wt, const float* Wp,
    const float* Wgx, const float* Wgb, const float* Wgd,
    const float* bgx, const float* bgb, const float* bgd,
    const float* Wwd, const float* Wwxb, const float* Wwb,
    const float* Wwxd, const float* Wwx,
    u16* wtp, u16* wg, u16* wf2, float* bg,
    float* __restrict__ ZZ)
{
    const int tid = threadIdx.x;
    if (blockIdx.z == 48) {
        int base = (blockIdx.y * 16 + blockIdx.x) * 1024;
        #pragma unroll
        for (int l = 0; l < 4; l++) {
            int t = base + l * 256 + tid;
            wtp[t] = f2bf(t < 32768 ? Wt[t] : Wp[t - 32768]);
            if (t < 32768) {
                wg[t] = f2bf(Wgx[t]); wg[32768 + t] = f2bf(Wgb[t]); wg[65536 + t] = f2bf(Wgd[t]);
            }
            {
                int o = t >> 8, k = t & 255, j = k & 127;
                const float* Wq[5] = {Wwd, Wwxb, Wwb, Wwxd, Wwx};
                #pragma unroll
                for (int q = 0; q < 5; q++)
                    wf2[q * 65536 + t] = f2bf(0.5f * Wq[q][o * 128 + j]);
            }
            if (t < 384) bg[t] = (t < 128) ? bgx[t] : (t < 256) ? bgb[t - 128] : bgd[t - 256];
            if (t < 13312) ZZ[t] = 0.0f;
        }
        return;
    }
    __shared__ float ls[64][68];
    const int z = blockIdx.z, which = z >> 4, b = z & 15;
    const float* src = (which == 0) ? x : (which == 1) ? ob : od;
    const float* s = src + (size_t)b * cC * cN;
    u16* dst = xt + (size_t)z * (cN * cC);
    const int n0 = blockIdx.x << 6, c0 = blockIdx.y << 6;

    const int cl0 = tid >> 4, n4 = (tid & 15) << 2;
    #pragma unroll
    for (int p = 0; p < 4; p++) {
        int cl = cl0 + (p << 4);
        f32x4 v = *(const f32x4*)&s[(size_t)(c0 + cl) * cN + n0 + n4];
        ls[cl][n4] = v[0]; ls[cl][n4 + 1] = v[1]; ls[cl][n4 + 2] = v[2]; ls[cl][n4 + 3] = v[3];
    }
    __syncthreads();
    const int nl0 = tid >> 3, c8 = (tid & 7) << 3;
    #pragma unroll
    for (int q = 0; q < 2; q++) {
        int nl = nl0 + (q << 5);
        short8 o;
        #pragma unroll
        for (int j = 0; j < 8; j++) o[j] = (short)f2bf(ls[c8 + j][nl]);
        *(short8*)&dst[(size_t)(n0 + nl) * 256 + c0 + c8] = o;
    }
}

// ---------------------------------------------------------------------------
extern "C" void kernel_launch(void* const* d_in, const int* in_sizes, int n_in,
                              void* d_out, int out_size, void* d_ws, size_t ws_size,
                              hipStream_t stream)
{
    const float* x    = (const float*)d_in[0];
    const float* ob   = (const float*)d_in[1];
    const float* od   = (const float*)d_in[2];
    const float* Wt   = (const float*)d_in[3];
    const float* Wp   = (const float*)d_in[4];
    const float* Wgx  = (const float*)d_in[5];
    const float* bgx  = (const float*)d_in[6];
    const float* Wgb  = (const float*)d_in[7];
    const float* bgb  = (const float*)d_in[8];
    const float* Wgd  = (const float*)d_in[9];
    const float* bgd  = (const float*)d_in[10];
    const float* Wwx  = (const float*)d_in[11];
    const float* bwx  = (const float*)d_in[12];
    const float* Wwb  = (const float*)d_in[13];
    const float* Wwd  = (const float*)d_in[15];
    const float* Wwxb = (const float*)d_in[17];
    const float* Wwxd = (const float*)d_in[19];
    const float* g1   = (const float*)d_in[21];
    const float* be1  = (const float*)d_in[22];
    const float* g2   = (const float*)d_in[23];
    const float* be2  = (const float*)d_in[24];
    const float* Wout = (const float*)d_in[25];
    const float* bout = (const float*)d_in[26];
    float* out = (float*)d_out;

    char* w = (char*)d_ws;
    u16*   XT    = (u16*)(w);                    // [3][16][1024][256]  25165824 B
    u16*   TP    = (u16*)(w + 25165824);         // [3][16][1024][256]  25165824 B (raw; reused as SALL)
    u16*   TPS   = (u16*)(w + 50331648);         // [3][16][1024][256]  25165824 B (scaled, n-major)
    u16*   TPSt  = (u16*)(w + 75497472);         // [3][16][256][1024]  25165824 B (scaled, c-major)
    u16*   G     = (u16*)(w + 100663296);        // [3][16][128][1024]  12582912 B (unscaled)
    u16*   MX    = (u16*)(w + 113246208);        // [16][256][256]      2097152 B
    u16*   MB    = (u16*)(w + 115343360);        // [16][256][512]      4194304 B
    u16*   MD    = (u16*)(w + 119537664);        // [16][256][512]      4194304 B
    u16*   FF2   = (u16*)(w + 123731968);        // [3][16][256][512]   12582912 B
    u16*   WTP   = (u16*)(w + 136314880);        // 131072 B
    u16*   WG    = (u16*)(w + 136445952);        // 196608 B
    u16*   WF2   = (u16*)(w + 136642560);        // [5][256][256]       655360 B
    u16*   WoutS = (u16*)(w + 137297920);        // [256][768]          393216 B
    float* BGf   = (float*)(w + 137691136);      // 2048 B
    float* BIAS2 = (float*)(w + 137693184);      // 4096 B
    float* ZZ    = (float*)(w + 137697280);      // 53248 B (CS | BNA, atomics)

    float* CS   = ZZ;                 // [48][256]
    float* BNA  = ZZ + 12288;         // [1024]
    u16*   SALL = TP;                 // [16][1024][768]; TP dead after tpt2

    // 1. prep + transpose + zero atomics region
    prep_transpose<<<dim3(16, 4, 49), 256, 0, stream>>>(
        x, ob, od, XT, Wt, Wp, Wgx, Wgb, Wgd, bgx, bgb, bgd,
        Wwd, Wwxb, Wwb, Wwxd, Wwx, WTP, WG, WF2, BGf, ZZ);

    // 2. TP = relu(XT @ WTP^T) + fused column sums -> CS
    tp_gemm<<<dim3(8, 1, 48), 512, 0, stream>>>(XT, WTP, TP, CS);

    // 3. d[n] in-block -> scaled TPS (n-major) + TPSt (c-major)
    tpt2<<<dim3(16, 1, 48), 256, 0, stream>>>(TP, CS, TPS, TPSt);

    // 4. unscaled G (no dinv dependency)
    g_gemm<<<dim3(8, 1, 48), 256, 0, stream>>>(XT, WG, BGf, G);

    // 5. inner factors, split-K=2 (TPSt scaled x G unscaled)
    inner_splitk<<<dim3(2, 2, 96), 256, 0, stream>>>(TPSt, G, MX, MB, MD);

    // 6. folds -> FF2
    fold_gemm<<<dim3(2, 1, 80), 512, 0, stream>>>(WF2, MX, MB, MD, FF2);

    // 7. outers (single dual-A K=512 core) -> SALL + BN stats
    outer_gemm<<<dim3(8, 1, 48), 512, 0, stream>>>(TPS, FF2, SALL, BNA);

    // 8. BN folded into Wout
    bnscale<<<dim3(256), 256, 0, stream>>>(Wout, g1, be1, g2, be2, bwx, bout,
                                           BNA, WoutS, BIAS2);

    // 9. out = WoutS @ SALL^T + BIAS2 + x  (K=768, plain write, 256 blocks)
    gemm_bt<128, 128, 2, 2, false, false, true, true><<<dim3(2, 8, 16), 256, 0, stream>>>(
        WoutS, 0, 0, 768,  SALL, 786432, 0, 768,  out, 262144, 0, 1024,
        768, BIAS2, 0, x, 262144);
}